// Round 14
// baseline (104.254 us; speedup 1.0000x reference)
//
#include <hip/hip_runtime.h>
#include <hip/hip_bf16.h>
#include <math.h>

// VectorQuantizer: z [65536 x 64] fp32, codebook [1024 x 64] fp32.
// dist = (||z||^2 - 2 z.e) + ||e||^2, argmin_k, first-occurrence ties.
// Numerics identical to R4-R17 (absmax 0): exact np pairwise sumsq for
// S/cn; d via f16 split-2 3-pass MFMA; dist = (S - 2d) + cn explicit
// __f*_rn; (val, lowest-k) reduce. MFMA accumulation order bit-exact.
//
// R21 post-mortem closed the budget: wall ~105k cy/SIMD; MFMA busy ~22k,
// VALU ~33k, ~50k BOTH-IDLE. Every register-load variant pulls 256KB of
// ef through L1 PER WAVE = 4MB/CU through the ~64B/cy vector-return port
// = ~65k cy -- structure-invariant; pipelining moves the wait, not the
// total. R8's LDS version cut traffic 16x but paid the __syncthreads
// vmcnt(0) DRAIN per tile (DMA serialized) + phase-lock. R23 = R8's
// traffic profile WITHOUT the drain (T3/T4 minimal 2-phase):
//   STAGE(t+1) -> s_waitcnt vmcnt(4) [tile t's loads done; t+1's stay
//   in flight] -> s_barrier [all quarters in] -> compute(t) ->
//   s_barrier [reads done before t+2 overwrites]. Raw asm barriers
//   ("memory"-clobbered, rule #18); vmcnt counted per m201/m218 recipe;
//   drained to 0 only at t=15.

#define D      64
#define K      1024
#define BLOCK  256

typedef _Float16 half8_t __attribute__((ext_vector_type(8)));
typedef float    floatx4 __attribute__((ext_vector_type(4)));

// ws layout
#define WS_CN_OFF    0            // float[1024]         (4 KB)
#define WS_EF_OFF    4096         // _Float16[131072]    (256 KB)
// per 64-code tile t (16 KB): frag (spl,ch,ct) at half-offset
//   t*8192 + 512*((spl*2+ch)*4+ct) + 8*lane

__device__ __forceinline__ void gld_lds16(const void* g, void* l) {
    __builtin_amdgcn_global_load_lds(
        (const __attribute__((address_space(1))) void*)g,
        (__attribute__((address_space(3))) void*)l, 16, 0, 0);
}

// numpy pairwise sumsq (n=64): 8 stride-8 accs of fl(x^2), tree combine.
__device__ __forceinline__ float np_sumsq64_p(const float* __restrict__ x) {
    float r[8];
    {
        float4 v0 = *(const float4*)(x);
        float4 v1 = *(const float4*)(x + 4);
        r[0] = __fmul_rn(v0.x, v0.x); r[1] = __fmul_rn(v0.y, v0.y);
        r[2] = __fmul_rn(v0.z, v0.z); r[3] = __fmul_rn(v0.w, v0.w);
        r[4] = __fmul_rn(v1.x, v1.x); r[5] = __fmul_rn(v1.y, v1.y);
        r[6] = __fmul_rn(v1.z, v1.z); r[7] = __fmul_rn(v1.w, v1.w);
    }
#pragma unroll
    for (int i = 8; i < 64; i += 8) {
        float4 v0 = *(const float4*)(x + i);
        float4 v1 = *(const float4*)(x + i + 4);
        r[0] = __fadd_rn(r[0], __fmul_rn(v0.x, v0.x));
        r[1] = __fadd_rn(r[1], __fmul_rn(v0.y, v0.y));
        r[2] = __fadd_rn(r[2], __fmul_rn(v0.z, v0.z));
        r[3] = __fadd_rn(r[3], __fmul_rn(v0.w, v0.w));
        r[4] = __fadd_rn(r[4], __fmul_rn(v1.x, v1.x));
        r[5] = __fadd_rn(r[5], __fmul_rn(v1.y, v1.y));
        r[6] = __fadd_rn(r[6], __fmul_rn(v1.z, v1.z));
        r[7] = __fadd_rn(r[7], __fmul_rn(v1.w, v1.w));
    }
    return __fadd_rn(__fadd_rn(__fadd_rn(r[0], r[1]), __fadd_rn(r[2], r[3])),
                     __fadd_rn(__fadd_rn(r[4], r[5]), __fadd_rn(r[6], r[7])));
}

// ---- precompute: code norms + f16 split-2 B-frags in MFMA lane order ----
__global__ void vq_pre(const float* __restrict__ cb, float* __restrict__ cn,
                       _Float16* __restrict__ ef) {
    const int k = blockIdx.x * 64 + threadIdx.x;
    if (k >= K) return;
    cn[k] = np_sumsq64_p(cb + (long)k * D);
    const int t = k >> 6, ct = (k >> 4) & 3, l16 = k & 15;
#pragma unroll
    for (int ch = 0; ch < 2; ++ch)
#pragma unroll
        for (int quad = 0; quad < 4; ++quad) {
            const float* p = cb + (long)k * D + ch * 32 + quad * 8;
            half8_t h1, h2;
#pragma unroll
            for (int j = 0; j < 8; ++j) {
                float x10 = __fmul_rn(p[j], 1024.0f);        // exact pow2 scale
                _Float16 g1 = (_Float16)x10;
                h1[j] = g1;
                h2[j] = (_Float16)(__fmul_rn(__fsub_rn(x10, (float)g1), 2048.0f));
            }
            const int base = t * 8192 + 128 * quad + 8 * l16;
            *(half8_t*)(ef + base + 512 * (ch * 4 + ct))       = h1;
            *(half8_t*)(ef + base + 512 * ((2 + ch) * 4 + ct)) = h2;
        }
}

// raw barrier / counted vmcnt (no compiler-inserted drains)
#define BAR()     asm volatile("s_barrier" ::: "memory")
#define VWAIT(n)  do { asm volatile("s_waitcnt vmcnt(" #n ")" ::: "memory");  \
                       __builtin_amdgcn_sched_barrier(0); } while (0)

// ---- main: 128 rows x ALL 1024 codes per 4-wave block; no-drain dbuf ----
__global__ __launch_bounds__(BLOCK, 2) void vq_main(
    const float* __restrict__ z, const float* __restrict__ cb,
    const _Float16* __restrict__ ef, const float* __restrict__ cn,
    float* __restrict__ zq, float* __restrict__ idx_out) {
    // zf (128 x 68 f32 = 34816 B) unioned with two 16 KB frag buffers
    __shared__ __align__(16) char smem[34816];
    __shared__ float sS[128];
    __shared__ float sCn[K];
    __shared__ int   sBi[128];
    float*    zf   = (float*)smem;
    _Float16* bufs = (_Float16*)smem;     // buf b at bufs + b*8192 (halfs)

    const int tid  = threadIdx.x;
    const int lane = tid & 63;
    const int wv   = tid >> 6;
    const int quad = lane >> 4;
    const int l16  = lane & 15;
    const long rowbase = (long)blockIdx.x * 128;

    // ---- stage z (coalesced) + all code norms ----
    const float4* gz = (const float4*)(z + rowbase * D);
#pragma unroll
    for (int i = 0; i < 8; ++i) {
        int idx4 = i * BLOCK + tid;
        int r = idx4 >> 4, j = idx4 & 15;
        *(float4*)(zf + r * 68 + j * 4) = gz[idx4];
    }
#pragma unroll
    for (int i = 0; i < 4; ++i) sCn[i * 256 + tid] = cn[i * 256 + tid];
    __syncthreads();

    // row norms (exact np chain)
    if (tid < 128) sS[tid] = np_sumsq64_p(zf + tid * 68);

    // A-frags: register-resident f16 splits; wave wv -> rows wv*32 .. +31
    half8_t a1[2][2], a2[2][2];
#pragma unroll
    for (int rt = 0; rt < 2; ++rt) {
        const int row = wv * 32 + rt * 16 + l16;
#pragma unroll
        for (int ch = 0; ch < 2; ++ch) {
            const float* p = zf + row * 68 + ch * 32 + quad * 8;
            float4 f0 = *(const float4*)(p);
            float4 f1 = *(const float4*)(p + 4);
            float xs[8] = {f0.x, f0.y, f0.z, f0.w, f1.x, f1.y, f1.z, f1.w};
#pragma unroll
            for (int j = 0; j < 8; ++j) {
                _Float16 h1 = (_Float16)xs[j];
                a1[rt][ch][j] = h1;
                a2[rt][ch][j] =
                    (_Float16)(__fmul_rn(__fsub_rn(xs[j], (float)h1), 2048.0f));
            }
        }
    }
    __syncthreads();   // all zf reads done; sS visible; smem reusable

    float myS[2][4];
#pragma unroll
    for (int rt = 0; rt < 2; ++rt)
#pragma unroll
        for (int r = 0; r < 4; ++r)
            myS[rt][r] = sS[wv * 32 + rt * 16 + quad * 4 + r];

    float bv[2][4];
    int   bi[2][4];
#pragma unroll
    for (int rt = 0; rt < 2; ++rt)
#pragma unroll
        for (int r = 0; r < 4; ++r) { bv[rt][r] = INFINITY; bi[rt][r] = 0; }

    const char* eb = (const char*)ef;
    const floatx4 Z4g = {0.f, 0.f, 0.f, 0.f};

// wave wv stages its 4 KB quarter of tile t_ (4 x gld_lds, vmcnt +=4)
#define STAGE(t_) do {                                                        \
        const char* g_ = eb + (size_t)(t_) * 16384 + wv * 4096 + lane * 16;   \
        char* l_ = (char*)bufs + (((t_) & 1) ? 16384 : 0) + wv * 4096;        \
        gld_lds16(g_,          l_);                                           \
        gld_lds16(g_ + 1024,   l_ + 1024);                                    \
        gld_lds16(g_ + 2048,   l_ + 2048);                                    \
        gld_lds16(g_ + 3072,   l_ + 3072);                                    \
    } while (0)

    // stage tile 0 (4 loads outstanding; no drain here)
    STAGE(0);

    for (int t = 0; t < 16; ++t) {
        if (t < 15) {
            STAGE(t + 1);          // +4 -> up to 8 outstanding
            VWAIT(4);              // oldest 4 (tile t) landed; t+1 in flight
        } else {
            VWAIT(0);              // tail: drain the last tile
        }
        BAR();                     // all waves' quarters of tile t in LDS

        const _Float16* cur = bufs + (t & 1) * 8192;
        const _Float16* tb  = cur + 8 * lane;
        const int kbase = t * 64;
#pragma unroll
        for (int ct = 0; ct < 4; ++ct) {
            half8_t b1[2], b2[2];
#pragma unroll
            for (int ch = 0; ch < 2; ++ch) {
                b1[ch] = *(const half8_t*)(tb + 512 * (ch * 4 + ct));
                b2[ch] = *(const half8_t*)(tb + 512 * ((2 + ch) * 4 + ct));
            }
            const int kg  = kbase + ct * 16 + l16;
            const float cnv = sCn[kg];

            // 12 MFMAs, rt0/rt1 interleaved; accumulation order = R8/R13
            floatx4 aM0, aM1, aC0, aC1;
            aM0 = __builtin_amdgcn_mfma_f32_16x16x32_f16(a1[0][0], b1[0], Z4g, 0, 0, 0);
            aM1 = __builtin_amdgcn_mfma_f32_16x16x32_f16(a1[1][0], b1[0], Z4g, 0, 0, 0);
            aM0 = __builtin_amdgcn_mfma_f32_16x16x32_f16(a1[0][1], b1[1], aM0, 0, 0, 0);
            aM1 = __builtin_amdgcn_mfma_f32_16x16x32_f16(a1[1][1], b1[1], aM1, 0, 0, 0);
            aC0 = __builtin_amdgcn_mfma_f32_16x16x32_f16(a1[0][0], b2[0], Z4g, 0, 0, 0);
            aC1 = __builtin_amdgcn_mfma_f32_16x16x32_f16(a1[1][0], b2[0], Z4g, 0, 0, 0);
            aC0 = __builtin_amdgcn_mfma_f32_16x16x32_f16(a1[0][1], b2[1], aC0, 0, 0, 0);
            aC1 = __builtin_amdgcn_mfma_f32_16x16x32_f16(a1[1][1], b2[1], aC1, 0, 0, 0);
            aC0 = __builtin_amdgcn_mfma_f32_16x16x32_f16(a2[0][0], b1[0], aC0, 0, 0, 0);
            aC1 = __builtin_amdgcn_mfma_f32_16x16x32_f16(a2[1][0], b1[0], aC1, 0, 0, 0);
            aC0 = __builtin_amdgcn_mfma_f32_16x16x32_f16(a2[0][1], b1[1], aC0, 0, 0, 0);
            aC1 = __builtin_amdgcn_mfma_f32_16x16x32_f16(a2[1][1], b1[1], aC1, 0, 0, 0);

            // exact EPI (R8/R13): ds=fma(aC,2^-11,aM); t2=ds*2^-9;
            // dist=(S-t2)+cn; strict < keeps first occurrence.
#pragma unroll
            for (int r = 0; r < 4; ++r) {
                float ds0 = fmaf(aC0[r], 0x1p-11f, aM0[r]);
                float d0  = __fadd_rn(__fsub_rn(myS[0][r],
                                __fmul_rn(ds0, 0x1p-9f)), cnv);
                if (d0 < bv[0][r]) { bv[0][r] = d0; bi[0][r] = kg; }
                float ds1 = fmaf(aC1[r], 0x1p-11f, aM1[r]);
                float d1  = __fadd_rn(__fsub_rn(myS[1][r],
                                __fmul_rn(ds1, 0x1p-9f)), cnv);
                if (d1 < bv[1][r]) { bv[1][r] = d1; bi[1][r] = kg; }
            }
        }
        BAR();   // all waves done reading buf[t&1] before t+2 overwrites it
    }

#undef STAGE

    // reduce over the 16 code-columns; (val, lowest index) = first occurrence
#pragma unroll
    for (int rt = 0; rt < 2; ++rt)
#pragma unroll
        for (int r = 0; r < 4; ++r) {
            float v = bv[rt][r];
            int   x = bi[rt][r];
#pragma unroll
            for (int off = 1; off <= 8; off <<= 1) {
                float ov = __shfl_xor(v, off);
                int   ox = __shfl_xor(x, off);
                if (ov < v || (ov == v && ox < x)) { v = ov; x = ox; }
            }
            if (l16 == 0) {
                const int rl = wv * 32 + rt * 16 + quad * 4 + r;
                sBi[rl] = x;
                idx_out[rowbase + rl] = (float)x;
            }
        }
    __syncthreads();

    // ---- zq gather: zq[row] = cb[bi[row]] (cb L2-hot, coalesced writes) ----
    const float4* cb4 = (const float4*)cb;
    float4* zq4 = (float4*)(zq + rowbase * D);
#pragma unroll
    for (int i = 0; i < 8; ++i) {
        int idx4 = i * BLOCK + tid;
        int r = idx4 >> 4, j = idx4 & 15;
        zq4[idx4] = cb4[(long)sBi[r] * 16 + j];
    }
}

extern "C" void kernel_launch(void* const* d_in, const int* in_sizes, int n_in,
                              void* d_out, int out_size, void* d_ws, size_t ws_size,
                              hipStream_t stream) {
    const float* z  = (const float*)d_in[0];
    const float* cb = (const float*)d_in[1];

    const int n_rows = in_sizes[0] / D;                 // 65536
    float* zq      = (float*)d_out;
    float* idx_out = zq + (long)n_rows * D;

    float*    ws_cn = (float*)((char*)d_ws + WS_CN_OFF);
    _Float16* ws_ef = (_Float16*)((char*)d_ws + WS_EF_OFF);

    vq_pre<<<K / 64, 64, 0, stream>>>(cb, ws_cn, ws_ef);
    vq_main<<<n_rows / 128, BLOCK, 0, stream>>>(z, cb, ws_ef, ws_cn, zq, idx_out);
}